// Round 7
// baseline (251.996 us; speedup 1.0000x reference)
//
#include <hip/hip_runtime.h>

// OTAM cumulative soft-min DTW — 2 problems per thread (ILP=2), all-register DP.
// dists: [200,200,32,32] f32 -> out[40000] f32 = cum[31][33].
//
// R6 post-mortem: thread-per-problem is chain-latency-bound (~190 eff cyc/cell;
// 625 waves -> ~0.6/SIMD, nothing hides the serial exp/log chain). Fix = ILP:
// each thread runs TWO independent problems (p and p+20000), interleaved
// statement-by-statement so chain B issues under chain A's latency.
// Per-cell-pair issue ~56 cyc overlaps the pair's chain latency.
//
// Math (identical to R6, absmax was 0.0):
//   row 0 = prefix sum of padded row.
//   rows 1..31 (lambda=0.5):
//     m=1    : v = d[l][0] + sm2(C2, prev[1])       (sm2(0,0)=C2 exact)
//     m=2..32: v = d[l][m-1] + sm2(prev[m-1], c)
//     m=33   : v = sm2(sm2(prev[32], c), prev[33])  (LSE associativity, d=0)
//   sm2(a,b) = min(a,b) + C2*log2(1 + 2^{K|a-b|}),  K=-2/ln2, C2=-ln2/2.
//
// In-place row update (save old prev[m] before overwrite) removes R6's np[34]
// array + 34-wide copy per row. launch_bounds(64,1) -> 512-VGPR cap; ~220 live
// regs (2x34 prev + 2x16 float4 bufs + temps), spill-free.

constexpr int HALF = 20000;

__global__ __launch_bounds__(64, 1) void otam_tpp2(const float* __restrict__ dists,
                                                   float* __restrict__ out) {
    const int t = blockIdx.x * 64 + threadIdx.x;
    if (t >= HALF) return;
    const float* dpA = dists + (size_t)t * 1024;
    const float* dpB = dists + (size_t)(t + HALF) * 1024;

    const float K = -2.8853900817779268f;    // -2/ln2
    const float C2 = -0.34657359027997264f;  // -ln2/2 == softmin2(0,0)

    auto sm2 = [&](float a, float b) {
        float mn = fminf(a, b);
        float e = __builtin_amdgcn_exp2f(K * __builtin_fabsf(a - b));  // <= 1
        return fmaf(C2, __builtin_amdgcn_logf(1.f + e), mn);
    };

    float prev[2][34];
    float4 buf[2][8];

    // ---- row 0: cumulative sums (both problems) ----
    {
        const float4* rA = (const float4*)dpA;
        const float4* rB = (const float4*)dpB;
#pragma unroll
        for (int i = 0; i < 8; ++i) { buf[0][i] = rA[i]; buf[1][i] = rB[i]; }
#pragma unroll
        for (int q = 0; q < 2; ++q) {
            float acc = 0.f;
#pragma unroll
            for (int i = 0; i < 8; ++i) {
                acc += buf[q][i].x; prev[q][4 * i + 1] = acc;
                acc += buf[q][i].y; prev[q][4 * i + 2] = acc;
                acc += buf[q][i].z; prev[q][4 * i + 3] = acc;
                acc += buf[q][i].w; prev[q][4 * i + 4] = acc;
            }
            prev[q][0] = 0.f;
            prev[q][33] = acc;  // pad col: +0
        }
    }

    // ---- prefetch row 1 ----
    {
        const float4* rA = (const float4*)(dpA + 32);
        const float4* rB = (const float4*)(dpB + 32);
#pragma unroll
        for (int i = 0; i < 8; ++i) { buf[0][i] = rA[i]; buf[1][i] = rB[i]; }
    }

    for (int l = 1; l < 32; ++l) {
        // double-buffer next row: 16 independent 16B loads hide under the
        // ~1800-cyc interleaved compute of this row.
        float4 nbuf[2][8];
        if (l < 31) {
            const float4* rA = (const float4*)(dpA + (l + 1) * 32);
            const float4* rB = (const float4*)(dpB + (l + 1) * 32);
#pragma unroll
            for (int i = 0; i < 8; ++i) { nbuf[0][i] = rA[i]; nbuf[1][i] = rB[i]; }
        }
        const float* dr0 = (const float*)buf[0];
        const float* dr1 = (const float*)buf[1];

        // m = 1: v = d + sm2(C2, prev[1]); old prev[1] saved into the rolling
        // "po" (old prev[m-1]) carried in-place through the row.
        float po0 = prev[0][1], po1 = prev[1][1];
        float c0 = dr0[0] + sm2(C2, po0);
        float c1 = dr1[0] + sm2(C2, po1);
        prev[0][1] = c0; prev[1][1] = c1;

#pragma unroll
        for (int m = 2; m <= 32; ++m) {
            float t0 = prev[0][m], t1 = prev[1][m];       // save old before overwrite
            c0 = dr0[m - 1] + sm2(po0, c0);               // chains A and B interleave:
            c1 = dr1[m - 1] + sm2(po1, c1);               // B issues under A's exp/log
            prev[0][m] = c0; prev[1][m] = c1;
            po0 = t0; po1 = t1;
        }

        // m = 33: d = 0 (pad); 3-term via exact LSE associativity
        float t0 = prev[0][33], t1 = prev[1][33];
        c0 = sm2(sm2(po0, c0), t0);
        c1 = sm2(sm2(po1, c1), t1);
        prev[0][33] = c0; prev[1][33] = c1;

#pragma unroll
        for (int i = 0; i < 8; ++i) { buf[0][i] = nbuf[0][i]; buf[1][i] = nbuf[1][i]; }
    }

    out[t] = prev[0][33];
    out[t + HALF] = prev[1][33];
}

extern "C" void kernel_launch(void* const* d_in, const int* in_sizes, int n_in,
                              void* d_out, int out_size, void* d_ws, size_t ws_size,
                              hipStream_t stream) {
    const float* dists = (const float*)d_in[0];
    float* out = (float*)d_out;
    dim3 grid((HALF + 63) / 64);  // 313 blocks x 64 threads, guard at 20000
    dim3 block(64);
    hipLaunchKernelGGL(otam_tpp2, grid, block, 0, stream, dists, out);
}